// Round 3
// baseline (382.155 us; speedup 1.0000x reference)
//
#include <hip/hip_runtime.h>

// ---- problem constants ----
#define TT 100
#define BB 1024
#define NI 256
#define NH 512
#define NO 10
#define TB (TT*BB)
#define GK 512                 // doubled K (hi/lo interleave)
#define GN 512
#define NCH 4                  // t-chunks
#define TCH 25

// output layout (floats), return order: cur1, cur2, spk1, spk2, mem1, mem2
constexpr long long C1_OFF = 0;
constexpr long long C2_OFF = 52428800LL;
constexpr long long S1_OFF = 53452800LL;
constexpr long long S2_OFF = 105881600LL;
constexpr long long M1_OFF = 106905600LL;
constexpr long long M2_OFF = 159334400LL;

typedef short bf16x8 __attribute__((ext_vector_type(8)));
typedef float f32x4 __attribute__((ext_vector_type(4)));

__device__ __forceinline__ unsigned int rne_bf16(float f) {
    unsigned int u = __float_as_uint(f);
    return (u + 0x7fffu + ((u >> 16) & 1u)) >> 16;
}

// f32 -> packed [hi,lo] bf16 pair (Dekker split), bit-identical to prior rounds
__device__ __forceinline__ unsigned int pack_hilo(float f) {
    unsigned int hi = rne_bf16(f);
    float hif = __uint_as_float(hi << 16);
    float e = f - hif;
    unsigned int lo = rne_bf16(e);
    return (hi & 0xffffu) | (lo << 16);
}

__device__ __forceinline__ void pack4(uint4& d, const float4& a) {
    d.x = pack_hilo(a.x); d.y = pack_hilo(a.y); d.z = pack_hilo(a.z); d.w = pack_hilo(a.w);
}

__device__ __forceinline__ void gload16(const void* g, void* l) {
    __builtin_amdgcn_global_load_lds(
        (const __attribute__((address_space(1))) void*)g,
        (__attribute__((address_space(3))) void*)l, 16, 0, 0);
}

// ---- prep: W1 (f32 {0,0.5}) -> pre-swizzled LDS-image (proven R1/R2) ----
__global__ void prep_w_kernel(const float* __restrict__ W1, short* __restrict__ Wimg) {
    int i = blockIdx.x * blockDim.x + threadIdx.x;
    if (i >= 4 * 16 * 128 * 4) return;
    int c16 = i & 3;
    int r   = (i >> 2) & 127;
    int kt  = (i >> 9) & 15;
    int p   = i >> 13;
    int usrc = c16 ^ ((r >> 1) & 3);
    int kbase = kt * 16 + usrc * 4;
    float4 w = *(const float4*)&W1[(long long)(p * 128 + r) * NI + kbase];
    float f[4] = {w.x, w.y, w.z, w.w};
    uint4 o;
    unsigned int* op = &o.x;
    #pragma unroll
    for (int j = 0; j < 4; ++j) {
        unsigned int hb = __float_as_uint(f[j]) >> 16;   // exact for 0 / 0.5
        op[j] = hb | (hb << 16);
    }
    ((uint4*)Wimg)[i] = o;
}

// ---- gemm role: one 128x128 tile of a t-chunk (proven R2 body) ----
__device__ __forceinline__ void gemm_role(
    const float* __restrict__ xc, const short* __restrict__ Wimg, float* __restrict__ Cc,
    int gid, int nPanels,
    short (&As)[2][128][40], short (&Ws)[2][128][32])
{
    const int tid = threadIdx.x;
    const int p = gid & 3;
    const int panel = gid >> 2;
    const int m0 = (nPanels - 1 - panel) * 128;   // reversed: high t written first
    const int n0 = p * 128;
    const int wid = tid >> 6;
    const int lane = tid & 63;
    const int wm = (wid >> 1) * 64;
    const int wn = (wid & 1) * 64;

    f32x4 acc[4][4] = {};

    const int srow = tid >> 2;
    const int sc4 = tid & 3;
    const long long ax0 = (long long)(m0 + srow) * NI + sc4 * 4;
    const long long ax1 = ax0 + 64LL * NI;

    const int fr = lane & 15;
    const int fk = (lane >> 4) * 8;
    const int swz = (((lane >> 4) ^ ((fr >> 1) & 3)) << 4);

    const short* wbase = Wimg + (long long)p * 16 * 4096;
    const int c0 = wid * 2;

    gload16(wbase + (c0    ) * 512 + lane * 8, (char*)&Ws[0][0][0] + (c0    ) * 1024);
    gload16(wbase + (c0 + 1) * 512 + lane * 8, (char*)&Ws[0][0][0] + (c0 + 1) * 1024);
    uint4 pa0, pa1;
    {
        float4 t0a = *(const float4*)&xc[ax0];
        float4 t0b = *(const float4*)&xc[ax1];
        uint4 q0, q1;
        pack4(q0, t0a); pack4(q1, t0b);
        *(uint4*)&As[0][srow][sc4 * 8]      = q0;
        *(uint4*)&As[0][srow + 64][sc4 * 8] = q1;
        float4 t1a = *(const float4*)&xc[ax0 + 16];
        float4 t1b = *(const float4*)&xc[ax1 + 16];
        pack4(pa0, t1a); pack4(pa1, t1b);
    }
    float4 raw0a = *(const float4*)&xc[ax0 + 32];
    float4 raw0b = *(const float4*)&xc[ax1 + 32];
    float4 raw1a = *(const float4*)&xc[ax0 + 48];
    float4 raw1b = *(const float4*)&xc[ax1 + 48];
    __syncthreads();

    #pragma unroll
    for (int kt = 0; kt < 16; ++kt) {
        const int cur = kt & 1;
        const int nxt = cur ^ 1;

        if (kt + 1 < 16) {
            const short* wt = wbase + (kt + 1) * 4096;
            gload16(wt + (c0    ) * 512 + lane * 8, (char*)&Ws[nxt][0][0] + (c0    ) * 1024);
            gload16(wt + (c0 + 1) * 512 + lane * 8, (char*)&Ws[nxt][0][0] + (c0 + 1) * 1024);
            *(uint4*)&As[nxt][srow][sc4 * 8]      = pa0;
            *(uint4*)&As[nxt][srow + 64][sc4 * 8] = pa1;
        }
        if (kt + 2 < 16) {
            if (cur == 0) { pack4(pa0, raw0a); pack4(pa1, raw0b); }
            else          { pack4(pa0, raw1a); pack4(pa1, raw1b); }
        }
        if (kt + 4 < 16) {
            if (cur == 0) {
                raw0a = *(const float4*)&xc[ax0 + (long long)(kt + 4) * 16];
                raw0b = *(const float4*)&xc[ax1 + (long long)(kt + 4) * 16];
            } else {
                raw1a = *(const float4*)&xc[ax0 + (long long)(kt + 4) * 16];
                raw1b = *(const float4*)&xc[ax1 + (long long)(kt + 4) * 16];
            }
        }

        bf16x8 af[4], wf[4];
        #pragma unroll
        for (int i = 0; i < 4; ++i) {
            af[i] = *(const bf16x8*)&As[cur][wm + i * 16 + fr][fk];
            wf[i] = *(const bf16x8*)((const char*)&Ws[cur][wn + i * 16 + fr][0] + swz);
        }
        #pragma unroll
        for (int i = 0; i < 4; ++i)
            #pragma unroll
            for (int j = 0; j < 4; ++j)
                acc[i][j] = __builtin_amdgcn_mfma_f32_16x16x32_bf16(af[i], wf[j], acc[i][j], 0, 0, 0);

        if (kt + 1 < 16) __syncthreads();
    }

    const int col = lane & 15;
    const int rbase = (lane >> 4) * 4;
    #pragma unroll
    for (int i = 0; i < 4; ++i) {
        #pragma unroll
        for (int j = 0; j < 4; ++j) {
            long long base = (long long)(m0 + wm + i * 16 + rbase) * GN + (n0 + wn + j * 16 + col);
            #pragma unroll
            for (int r = 0; r < 4; ++r)
                Cc[base + (long long)r * GN] = acc[i][j][r];
        }
    }
}

// ---- lif role: LIF1 + popcount-GEMM2 + LIF2 for one b, t in [t0,t1) ----
// 256 threads, 2 h per thread; arithmetic identical to the 512-thread version.
__device__ __forceinline__ void lif_role(
    const float* __restrict__ cur1, const float* __restrict__ W2, float* __restrict__ out,
    int b, int t0, int t1,
    unsigned long long (&wmks)[2][8], unsigned long long (&w2ms)[NO][8])
{
    const int tid = threadIdx.x;     // 0..255
    const int w = tid >> 6;          // 0..3
    const int lane = tid & 63;
    const int h0 = tid, h1 = tid + 256;

    #pragma unroll
    for (int o = 0; o < NO; ++o) {
        unsigned long long mk0 = __ballot(W2[o * NH + h0] != 0.0f);
        unsigned long long mk1 = __ballot(W2[o * NH + h1] != 0.0f);
        if (lane == 0) { w2ms[o][w] = mk0; w2ms[o][4 + w] = mk1; }
    }
    __syncthreads();
    unsigned long long w2m[8];
    if (tid < NO) {
        #pragma unroll
        for (int i = 0; i < 8; ++i) w2m[i] = w2ms[tid][i];
    }

    const long long st1 = (long long)BB * NH;
    const long long i0 = (long long)b * NH + h0;
    const long long i1 = (long long)b * NH + h1;
    const float* cap = cur1 + i0;
    const float* cbp = cur1 + i1;
    float* sap = out + S1_OFF + i0;  float* sbp = out + S1_OFF + i1;
    float* map = out + M1_OFF + i0;  float* mbp = out + M1_OFF + i1;

    float m1a = 0.0f, m1b = 0.0f, m2 = 0.0f;
    if (t0 != 0) {
        m1a = map[(long long)(t0 - 1) * st1];
        m1b = mbp[(long long)(t0 - 1) * st1];
        if (tid < NO) m2 = out[M2_OFF + (long long)(t0 - 1) * (BB * NO) + b * NO + tid];
    }

    float ca = cap[(long long)t0 * st1];
    float cb = cbp[(long long)t0 * st1];
    for (int t = t0; t < t1; ++t) {
        float can = 0.0f, cbn = 0.0f;
        if (t + 1 < t1) {
            can = cap[(long long)(t + 1) * st1];
            cbn = cbp[(long long)(t + 1) * st1];
        }

        float rsta = (m1a > 1.0f) ? 1.0f : 0.0f;
        m1a = 0.9f * m1a + ca - rsta;
        float s1a = (m1a > 1.0f) ? 1.0f : 0.0f;
        float rstb = (m1b > 1.0f) ? 1.0f : 0.0f;
        m1b = 0.9f * m1b + cb - rstb;
        float s1b = (m1b > 1.0f) ? 1.0f : 0.0f;
        sap[(long long)t * st1] = s1a;  map[(long long)t * st1] = m1a;
        sbp[(long long)t * st1] = s1b;  mbp[(long long)t * st1] = m1b;

        unsigned long long mk0 = __ballot(s1a != 0.0f);
        unsigned long long mk1 = __ballot(s1b != 0.0f);
        if (lane == 0) { wmks[t & 1][w] = mk0; wmks[t & 1][4 + w] = mk1; }
        __syncthreads();

        if (tid < NO) {
            int cnt = 0;
            #pragma unroll
            for (int i = 0; i < 8; ++i) cnt += __popcll(wmks[t & 1][i] & w2m[i]);
            float c2 = 0.5f * (float)cnt;
            float rst2 = (m2 > 1.0f) ? 1.0f : 0.0f;
            m2 = 0.8f * m2 + c2 - rst2;
            float s2 = (m2 > 1.0f) ? 1.0f : 0.0f;
            long long o2 = (long long)t * (BB * NO) + b * NO + tid;
            out[C2_OFF + o2] = c2;
            out[S2_OFF + o2] = s2;
            out[M2_OFF + o2] = m2;
        }
        ca = can; cb = cbn;
        // no second barrier: wmks double-buffered by t&1
    }
}

// ---- joint kernel: gemm blocks for chunk c, lif blocks for chunk c-1 ----
// Roles are data-independent within a launch; dependency carried by launch order.
__launch_bounds__(256, 2)
__global__ void joint_kernel(const float* __restrict__ xc, const short* __restrict__ Wimg,
                             float* __restrict__ Cc, const float* __restrict__ cur1,
                             const float* __restrict__ W2, float* __restrict__ out,
                             int nPanels, int lifT0, int lifT1)
{
    __shared__ short As[2][128][40];
    __shared__ short Ws[2][128][32];
    __shared__ unsigned long long wmks[2][8];
    __shared__ unsigned long long w2ms[NO][8];

    const int bid = blockIdx.x;
    const int G = nPanels * 4;
    const int total = gridDim.x;
    // Bresenham split: exactly G gemm blocks, evenly interleaved with lif blocks
    const long long a = (long long)bid * G / total;
    const long long bc = (long long)(bid + 1) * G / total;
    if (bc > a) {
        gemm_role(xc, Wimg, Cc, (int)a, nPanels, As, Ws);
    } else {
        lif_role(cur1, W2, out, (int)(bid - bc), lifT0, lifT1, wmks, w2ms);
    }
}

extern "C" void kernel_launch(void* const* d_in, const int* in_sizes, int n_in,
                              void* d_out, int out_size, void* d_ws, size_t ws_size,
                              hipStream_t stream) {
    const float* x  = (const float*)d_in[0];
    const float* W1 = (const float*)d_in[1];
    const float* W2 = (const float*)d_in[2];
    float* out = (float*)d_out;

    // W image (512KB) in the LAST lif chunk's S1 slice: its final gemm consumer
    // runs in launch NCH-1; only launch NCH (lif chunk NCH-1) overwrites it.
    short* Wp = (short*)(out + S1_OFF + (long long)(NCH - 1) * TCH * BB * NH);
    float* C1 = out + C1_OFF;

    {
        int units = NH * GK / 8;   // 32,768 16B-units
        prep_w_kernel<<<(units + 255) / 256, 256, 0, stream>>>(W1, Wp);
    }
    // pipeline: launch i = gemm chunk i (i<NCH) + lif chunk i-1 (i>=1)
    for (int i = 0; i <= NCH; ++i) {
        const bool g = (i < NCH);
        const bool l = (i >= 1);
        const int gt0 = g ? i * TCH : 0;
        const int nP  = g ? TCH * BB / 128 : 0;   // 200 panels
        const int G   = nP * 4;                    // 800 gemm blocks
        const int L   = l ? BB : 0;                // 1024 lif blocks
        joint_kernel<<<G + L, 256, 0, stream>>>(
            x + (long long)gt0 * BB * NI, Wp, C1 + (long long)gt0 * BB * GN,
            C1, W2, out,
            nP, l ? (i - 1) * TCH : 0, l ? i * TCH : 0);
    }
}

// Round 4
// 354.349 us; speedup vs baseline: 1.0785x; 1.0785x over previous
//
#include <hip/hip_runtime.h>

// ---- problem constants ----
#define TT 100
#define BB 1024
#define NI 256
#define NH 512
#define NO 10
#define GK 512                 // doubled K (hi/lo interleave)

// output layout (floats), return order: cur1, cur2, spk1, spk2, mem1, mem2
constexpr long long C1_OFF = 0;
constexpr long long C2_OFF = 52428800LL;
constexpr long long S1_OFF = 53452800LL;
constexpr long long S2_OFF = 105881600LL;
constexpr long long M1_OFF = 106905600LL;
constexpr long long M2_OFF = 159334400LL;

typedef short bf16x8 __attribute__((ext_vector_type(8)));
typedef float f32x4 __attribute__((ext_vector_type(4)));

__device__ __forceinline__ unsigned int rne_bf16(float f) {
    unsigned int u = __float_as_uint(f);
    return (u + 0x7fffu + ((u >> 16) & 1u)) >> 16;
}

// f32 -> packed [hi,lo] bf16 pair (Dekker split), bit-identical to prior rounds
__device__ __forceinline__ unsigned int pack_hilo(float f) {
    unsigned int hi = rne_bf16(f);
    float hif = __uint_as_float(hi << 16);
    float e = f - hif;
    unsigned int lo = rne_bf16(e);
    return (hi & 0xffffu) | (lo << 16);
}

__device__ __forceinline__ void pack4(uint4& d, const float4& a) {
    d.x = pack_hilo(a.x); d.y = pack_hilo(a.y); d.z = pack_hilo(a.z); d.w = pack_hilo(a.w);
}

// ---- prep: W1 (f32 {0,0.5}) -> bf16 duplicated pairs, linear [h][gk] ----
__global__ void prep_w_kernel(const float* __restrict__ W1, short* __restrict__ Wp) {
    int i = blockIdx.x * blockDim.x + threadIdx.x;
    if (i >= NH * NI / 4) return;
    float4 v = ((const float4*)W1)[i];
    float f[4] = {v.x, v.y, v.z, v.w};
    uint4 o;
    unsigned int* op = &o.x;
    #pragma unroll
    for (int j = 0; j < 4; ++j) {
        unsigned int hb = __float_as_uint(f[j]) >> 16;   // exact for 0 / 0.5
        op[j] = hb | (hb << 16);
    }
    ((uint4*)Wp)[i] = o;
}

// ---- zero C2 (atomic accumulation target) ----
__global__ void zero_c2_kernel(float* __restrict__ c2) {
    int i = blockIdx.x * blockDim.x + threadIdx.x;
    if (i < TT * BB * NO / 4) ((float4*)c2)[i] = float4{0.f, 0.f, 0.f, 0.f};
}

// ---- fused GEMM1 + LIF1 + partial GEMM2 (atomic) ----
// Block owns (32 b) x (64 h) for ALL t; W1 chunk LDS-resident (swizzled);
// m1 in registers across t. Per t: stage x (dbuf, 2-deep reg prefetch),
// 16-kt MFMA chain (same order as R2 -> bit-identical cur1), in-register LIF1,
// store c1/s1/m1 (store-only), ballot spikes, atomicAdd 0.5*popcnt partial
// cur2 into C2 (exact halves -> order-independent). One barrier per t.
__launch_bounds__(512, 1)
__global__ void fused_kernel(const float* __restrict__ x, const short* __restrict__ Wp,
                             const float* __restrict__ W2, float* __restrict__ out) {
    __shared__ short Wl[64][512];          // 64 KB resident W chunk (16B-unit XOR swz)
    __shared__ short Al[2][32][512];       // 64 KB x-tile double buffer (same swz)
    __shared__ unsigned long long bal[2][8][4];
    __shared__ unsigned long long w2m_lds[NO];

    const int tid = threadIdx.x;
    const int bid = blockIdx.x;
    // XCD grouping: 8 h-chunk blocks of one b-group share an XCD (bid&7)
    const int xcd = bid & 7;
    const int j8  = bid >> 3;              // 0..31
    const int bgrp = xcd * 4 + (j8 >> 3);  // 0..31 (bijective)
    const int nc   = j8 & 7;               // 0..7
    const int b0 = bgrp * 32;
    const int n0 = nc * 64;

    const int wid = tid >> 6;              // 0..7 (2m x 4n waves)
    const int lane = tid & 63;
    const int mw = wid >> 2;               // 0..1
    const int nw = wid & 3;                // 0..3
    const int fr = lane & 15;
    const int g  = lane >> 4;              // 0..3
    const int mrow = mw * 16 + fr;
    const int nrow = nw * 16 + fr;

    // ---- prologue ----
    if (wid == 0) {
        #pragma unroll
        for (int o = 0; o < NO; ++o)
            w2m_lds[o] = __ballot(W2[o * NH + n0 + lane] != 0.0f);
    }
    #pragma unroll
    for (int u8 = 0; u8 < 8; ++u8) {       // W chunk: 4096 16B units, coalesced
        int e = u8 * 512 + tid;
        int r = e >> 6, u = e & 63;
        uint4 v = ((const uint4*)Wp)[(long long)n0 * 64 + e];
        *(uint4*)&Wl[r][((u ^ (r & 7)) * 8)] = v;
    }
    const int arow = tid >> 4;             // 0..31
    const int au0 = (tid & 15) * 4;
    {
        const float* xs = x + ((long long)b0 + arow) * NI;
        #pragma unroll
        for (int uu = 0; uu < 4; ++uu) {
            float4 a = *(const float4*)&xs[(au0 + uu) * 4];
            uint4 pa; pack4(pa, a);
            *(uint4*)&Al[0][arow][(((au0 + uu) ^ (arow & 7)) * 8)] = pa;
        }
    }
    float4 rawOdd[4], rawEven[4];          // x(1) / x(2)
    #pragma unroll
    for (int uu = 0; uu < 4; ++uu) {
        rawOdd[uu]  = *(const float4*)&x[((long long)1 * BB + b0 + arow) * NI + (au0 + uu) * 4];
        rawEven[uu] = *(const float4*)&x[((long long)2 * BB + b0 + arow) * NI + (au0 + uu) * 4];
    }
    __syncthreads();
    unsigned long long w2m_reg = (tid < 32 * NO) ? w2m_lds[tid >> 5] : 0ULL;

    float m1v[4] = {0.f, 0.f, 0.f, 0.f};

    auto step = [&](int T, float4 (&RAW)[4]) {
        f32x4 a = {0.f, 0.f, 0.f, 0.f};
        #pragma unroll
        for (int kt = 0; kt < 16; ++kt) {
            bf16x8 af = *(const bf16x8*)&Al[T & 1][mrow][(((kt * 4 + g) ^ (fr & 7)) * 8)];
            bf16x8 wf = *(const bf16x8*)&Wl[nrow][(((kt * 4 + g) ^ (fr & 7)) * 8)];
            a = __builtin_amdgcn_mfma_f32_16x16x32_bf16(af, wf, a, 0, 0, 0);
        }
        float s1v[4];
        #pragma unroll
        for (int r = 0; r < 4; ++r) {
            float c1 = a[r];
            float rst = (m1v[r] > 1.0f) ? 1.0f : 0.0f;
            m1v[r] = 0.9f * m1v[r] + c1 - rst;
            s1v[r] = (m1v[r] > 1.0f) ? 1.0f : 0.0f;
            long long ob = ((long long)T * BB + b0 + mw * 16 + g * 4 + r) * NH + n0 + nw * 16 + fr;
            out[C1_OFF + ob] = c1;
            out[S1_OFF + ob] = s1v[r];
            out[M1_OFF + ob] = m1v[r];
        }
        #pragma unroll
        for (int r = 0; r < 4; ++r) {
            unsigned long long bm = __ballot(s1v[r] != 0.0f);
            if (lane == 0) bal[T & 1][wid][r] = bm;
        }
        if (T + 1 < TT) {
            #pragma unroll
            for (int uu = 0; uu < 4; ++uu) {
                uint4 pa; pack4(pa, RAW[uu]);
                *(uint4*)&Al[(T + 1) & 1][arow][(((au0 + uu) ^ (arow & 7)) * 8)] = pa;
            }
            int tl = (T + 3 < TT) ? T + 3 : TT - 1;
            #pragma unroll
            for (int uu = 0; uu < 4; ++uu)
                RAW[uu] = *(const float4*)&x[((long long)tl * BB + b0 + arow) * NI + (au0 + uu) * 4];
        }
        __syncthreads();
        if (tid < 32 * NO) {
            int r = tid & 31, o = tid >> 5;
            int mwr = r >> 4, l15 = r & 15;
            unsigned long long row64 = 0;
            #pragma unroll
            for (int nwx = 0; nwx < 4; ++nwx)
                row64 |= ((bal[T & 1][mwr * 4 + nwx][l15 & 3] >> ((l15 >> 2) * 16)) & 0xFFFFULL)
                         << (16 * nwx);
            int cnt = __popcll(row64 & w2m_reg);
            atomicAdd(out + C2_OFF + ((long long)T * BB + b0 + r) * NO + o, 0.5f * (float)cnt);
        }
    };

    for (int tp = 0; tp < TT; tp += 2) {
        step(tp,     rawOdd);
        step(tp + 1, rawEven);
    }
}

// ---- LIF2: m2 recurrence over completed C2 (4 MB, L3-hot) ----
__launch_bounds__(512)
__global__ void lif2_kernel(float* __restrict__ out) {
    int j = blockIdx.x * 512 + threadIdx.x;
    if (j >= BB * NO) return;
    const float* c2p = out + C2_OFF + j;
    float* s2p = out + S2_OFF + j;
    float* m2p = out + M2_OFF + j;
    const int st = BB * NO;
    float m2 = 0.f;
    float v[4];
    #pragma unroll
    for (int k = 0; k < 4; ++k) v[k] = c2p[(long long)k * st];
    for (int t = 0; t < TT; t += 4) {
        #pragma unroll
        for (int k = 0; k < 4; ++k) {
            float c2 = v[k];
            if (t + 4 + k < TT) v[k] = c2p[(long long)(t + 4 + k) * st];
            float rst = (m2 > 1.0f) ? 1.0f : 0.0f;
            m2 = 0.8f * m2 + c2 - rst;
            float s2 = (m2 > 1.0f) ? 1.0f : 0.0f;
            s2p[(long long)(t + k) * st] = s2;
            m2p[(long long)(t + k) * st] = m2;
        }
    }
}

extern "C" void kernel_launch(void* const* d_in, const int* in_sizes, int n_in,
                              void* d_out, int out_size, void* d_ws, size_t ws_size,
                              hipStream_t stream) {
    const float* x  = (const float*)d_in[0];
    const float* W1 = (const float*)d_in[1];
    const float* W2 = (const float*)d_in[2];
    float* out = (float*)d_out;

    // Wp scratch (512 KB) in the S2 region: read only by fused_kernel's prologue,
    // overwritten only by lif2_kernel (strictly after). Stream-ordered safe.
    short* Wp = (short*)(out + S2_OFF);

    prep_w_kernel<<<(NH * NI / 4 + 255) / 256, 256, 0, stream>>>(W1, Wp);
    zero_c2_kernel<<<(TT * BB * NO / 4 + 255) / 256, 256, 0, stream>>>(out + C2_OFF);
    fused_kernel<<<256, 512, 0, stream>>>(x, Wp, W2, out);
    lif2_kernel<<<(BB * NO + 511) / 512, 512, 0, stream>>>(out);
}